// Round 16
// baseline (156.473 us; speedup 1.0000x reference)
//
#include <hip/hip_runtime.h>

typedef unsigned short u16;
typedef unsigned int u32;
typedef __attribute__((ext_vector_type(8))) short bf16x8;
typedef __attribute__((ext_vector_type(4))) short bf16x4;
typedef __attribute__((ext_vector_type(4))) float f32x4;

#define MFMA16(a, b, c) __builtin_amdgcn_mfma_f32_16x16x32_bf16(a, b, c, 0, 0, 0)
#define MFMAK16(a, b, c) __builtin_amdgcn_mfma_f32_16x16x16bf16_1k(a, b, c, 0, 0, 0)

__device__ __forceinline__ float hw_exp2(float x) { return __builtin_amdgcn_exp2f(x); }

__device__ __forceinline__ u16 f2bf(float f) {
    union { float f; u32 i; } v; v.f = f;
    u32 x = v.i;
    return (u16)((x + 0x7FFFu + ((x >> 16) & 1u)) >> 16);
}

// ---------------- kernel 1: prep ----------------
__global__ __launch_bounds__(256) void k_prep(const float* __restrict__ x,
                                              const float* __restrict__ wqkv,
                                              const float* __restrict__ wout,
                                              u16* __restrict__ xb,
                                              u16* __restrict__ wqkvT,
                                              u16* __restrict__ woutT) {
    const float QSCALE2 = 0.2550566756538019f;  // 32^-0.5 * log2(e)
    int bx = blockIdx.x, tid = threadIdx.x;
    if (bx < 1024) {
        int base = bx * 2048 + tid * 8;
        float4 a = *(const float4*)(x + base);
        float4 b = *(const float4*)(x + base + 4);
        uint4 r;
        r.x = f2bf(a.x) | ((u32)f2bf(a.y) << 16);
        r.y = f2bf(a.z) | ((u32)f2bf(a.w) << 16);
        r.z = f2bf(b.x) | ((u32)f2bf(b.y) << 16);
        r.w = f2bf(b.z) | ((u32)f2bf(b.w) << 16);
        *(uint4*)(xb + base) = r;
    } else if (bx < 1792) {
        int idx = (bx - 1024) * 256 + tid;
        int n = idx >> 8, kk = idx & 255;
        float sc = (n < 256) ? QSCALE2 : 1.0f;
        wqkvT[idx] = f2bf(wqkv[kk * 768 + n] * sc);
    } else {
        int idx = (bx - 1792) * 256 + tid;
        int n = idx >> 8, kk = idx & 255;
        woutT[idx] = f2bf(wout[kk * 256 + n]);
    }
}

// ---------------- kernel 2: qkv = xb @ w_qkv, LDS-coalesced epilogue ----------------
__global__ __launch_bounds__(256) void k_gemm_qkv(const u16* __restrict__ xb,
                                                  const u16* __restrict__ wT,
                                                  u16* __restrict__ qkv) {
    __shared__ __align__(16) u16 slds[8704];  // QK: [128][68]; V: [64][136]
    const int tid = threadIdx.x;
    const int wave = tid >> 6, lane = tid & 63, quad = lane >> 4, ql = lane & 15;
    const int mbase = blockIdx.x * 128 + (wave & 1) * 64;
    const int nbase = blockIdx.y * 64 + (wave >> 1) * 32;
    f32x4 acc[4][2];
#pragma unroll
    for (int i = 0; i < 4; ++i)
#pragma unroll
        for (int j = 0; j < 2; ++j) acc[i][j] = (f32x4){0.f, 0.f, 0.f, 0.f};
#pragma unroll
    for (int ks = 0; ks < 8; ++ks) {
        bf16x8 af[4], bfm[2];
#pragma unroll
        for (int ms = 0; ms < 4; ++ms)
            af[ms] = *(const bf16x8*)(xb + (size_t)(mbase + ms * 16 + ql) * 256 + ks * 32 + quad * 8);
#pragma unroll
        for (int ns = 0; ns < 2; ++ns)
            bfm[ns] = *(const bf16x8*)(wT + (size_t)(nbase + ns * 16 + ql) * 256 + ks * 32 + quad * 8);
#pragma unroll
        for (int ms = 0; ms < 4; ++ms)
#pragma unroll
            for (int ns = 0; ns < 2; ++ns)
                acc[ms][ns] = MFMA16(af[ms], bfm[ns], acc[ms][ns]);
    }

    const int t = (blockIdx.y * 64) >> 8;  // 0=Q, 1=K, 2=V (uniform per block)
    if (t < 2) {
        const int rowb = (wave & 1) * 64, colb = (wave >> 1) * 32;
#pragma unroll
        for (int ms = 0; ms < 4; ++ms)
#pragma unroll
            for (int ns = 0; ns < 2; ++ns)
#pragma unroll
                for (int r = 0; r < 4; ++r)
                    slds[(rowb + ms * 16 + quad * 4 + r) * 68 + colb + ns * 16 + ql] =
                        f2bf(acc[ms][ns][r]);
        __syncthreads();
        u16* base = qkv + (size_t)t * 2097152;
#pragma unroll
        for (int p = 0; p < 8; ++p) {
            int c = p * 256 + tid;
            int row = c >> 4, ch = c & 15;
            uint2 w = *(const uint2*)&slds[row * 68 + ch * 4];
            int n = blockIdx.x * 128 + row;
            int col = blockIdx.y * 64 + ch * 4;
            int h = (col & 255) >> 5, d = col & 31;
            *(uint2*)(base + ((size_t)((n >> 11) * 8 + h) * 2048 + (n & 2047)) * 32 + d) = w;
        }
    } else {
        const int hl = wave >> 1, nb = (wave & 1) * 64;
#pragma unroll
        for (int ms = 0; ms < 4; ++ms)
#pragma unroll
            for (int ns = 0; ns < 2; ++ns) {
                u16 e0 = f2bf(acc[ms][ns][0]), e1 = f2bf(acc[ms][ns][1]);
                u16 e2 = f2bf(acc[ms][ns][2]), e3 = f2bf(acc[ms][ns][3]);
                uint2 pp; pp.x = e0 | ((u32)e1 << 16); pp.y = e2 | ((u32)e3 << 16);
                *(uint2*)&slds[(hl * 32 + ns * 16 + ql) * 136 + nb + ms * 16 + quad * 4] = pp;
            }
        __syncthreads();
        u16* vbase = qkv + (size_t)2 * 2097152;
#pragma unroll
        for (int p = 0; p < 4; ++p) {
            int c = p * 256 + tid;
            int row = c >> 4, ch = c & 15;
            bf16x8 w = *(const bf16x8*)&slds[row * 136 + ch * 8];
            int n0 = blockIdx.x * 128 + ch * 8;
            int h = (blockIdx.y & 3) * 2 + (row >> 5), d = row & 31;
            *(bf16x8*)(vbase + (size_t)((n0 >> 11) * 8 + h) * 65536 +
                       (size_t)d * 2048 + (n0 & 2047)) = w;
        }
    }
}

// ---------------- kernel 3: split-K flash attention (unchanged from r15) ----------------
__global__ __launch_bounds__(256, 4) void k_attn(const u16* __restrict__ q,
                                                 const u16* __restrict__ k,
                                                 const u16* __restrict__ vT,
                                                 const float* __restrict__ table,
                                                 float* __restrict__ Opart,
                                                 float* __restrict__ lpart) {
    __shared__ __align__(16) u16 kbuf[2][2][2048];  // [buf][tile][swizzled 64x32]
    __shared__ __align__(16) u16 vbuf[2][2][2048];  // [buf][tile][32 d][64 n swizzled]
    __shared__ float tbl2[1160];
    const int tid = threadIdx.x;
    const int bh = blockIdx.x & 31, qt = (blockIdx.x >> 5) & 15, kh = blockIdx.x >> 9;
    const int wave = tid >> 6, lane = tid & 63, quad = lane >> 4, ql = lane & 15;
    const float LOG2E = 1.4426950408889634f;

    const u16* kbh = k + (size_t)bh * 65536;
    const u16* vbh = vT + (size_t)bh * 65536;  // [32 d][2048 n]

    const int krow = wave * 16 + (lane >> 2);
    const u16* kg = kbh + kh * 32768 + krow * 32 + ((((lane & 3) ^ ((lane >> 3) & 3))) << 3);
    const int vd = wave * 8 + (lane >> 3);
    const u16* vg = vbh + (size_t)vd * 2048 + kh * 1024 + (((lane & 7) ^ (vd & 7)) << 3);

#define GLDS(SRC, DST) __builtin_amdgcn_global_load_lds(                         \
        (const __attribute__((address_space(1))) void*)(SRC),                    \
        (__attribute__((address_space(3))) void*)(DST), 16, 0, 0)
#define DMA(BUF, PAIR) do {                                                      \
    GLDS(kg + (PAIR) * 4096,        &kbuf[BUF][0][wave * 512]);                  \
    GLDS(kg + (PAIR) * 4096 + 2048, &kbuf[BUF][1][wave * 512]);                  \
    GLDS(vg + (PAIR) * 128,         &vbuf[BUF][0][wave * 512]);                  \
    GLDS(vg + (PAIR) * 128 + 64,    &vbuf[BUF][1][wave * 512]);                  \
} while (0)

    DMA(0, 0);  // pair 0 in flight during bias staging

    // bias window for this (qt,kh): global base = qt*128 - kh*1024 + 1024, width 1151.
    const float4* tg = (const float4*)(table + qt * 128 - kh * 1024 + 1024);
    for (int i = tid; i < 288; i += 256) {
        float4 t = tg[i];
        t.x *= LOG2E; t.y *= LOG2E; t.z *= LOG2E; t.w *= LOG2E;
        ((float4*)tbl2)[i] = t;
    }

    const int qr0 = qt * 128 + wave * 32 + ql;
    bf16x8 qf[2];
    qf[0] = *(const bf16x8*)(q + ((size_t)bh * 2048 + qr0) * 32 + quad * 8);
    qf[1] = *(const bf16x8*)(q + ((size_t)bh * 2048 + qr0 + 16) * 32 + quad * 8);
    const int bloc0 = wave * 32 + ql + 1023 - quad * 4;  // local window index base
    const int kro = ((quad ^ ((ql >> 1) & 3)) << 3);     // K read swizzle offset

    bf16x4 ones4;
#pragma unroll
    for (int i = 0; i < 4; ++i) ones4[i] = (short)0x3F80;  // bf16 1.0

    f32x4 oT0[2], oT1[2], oL[2];
#pragma unroll
    for (int qh = 0; qh < 2; ++qh) {
        oT0[qh] = (f32x4){0.f, 0.f, 0.f, 0.f};
        oT1[qh] = (f32x4){0.f, 0.f, 0.f, 0.f};
        oL[qh]  = (f32x4){0.f, 0.f, 0.f, 0.f};
    }

    __syncthreads();  // bias + pair 0 ready

    for (int pr = 0; pr < 8; ++pr) {
        const int buf = pr & 1;
        if (pr < 7) DMA(buf ^ 1, pr + 1);  // lands during this 2-tile body

#pragma unroll
        for (int t = 0; t < 2; ++t) {
            const int ktl = pr * 2 + t;  // local tile 0..15
            const u16* kb = &kbuf[buf][t][0];
            const u16* vb = &vbuf[buf][t][0];
            bf16x8 kf[4];
            bf16x4 va[2][4];  // [d-tile][j]: A-frag of V^T, k = quad*4 + reg
#pragma unroll
            for (int j = 0; j < 4; ++j)
                kf[j] = *(const bf16x8*)(kb + (j * 16 + ql) * 32 + kro);
#pragma unroll
            for (int dt = 0; dt < 2; ++dt)
#pragma unroll
                for (int j = 0; j < 4; ++j) {
                    int nloc = j * 16 + quad * 4;
                    int slot = (nloc >> 3) ^ (ql & 7);
                    va[dt][j] = *(const bf16x4*)(vb + (dt * 16 + ql) * 64 +
                                                 slot * 8 + (nloc & 7));
                }
            // bias groups: grp = qh - j + 3 in 0..4
            const int bkt = bloc0 - ktl * 64;
            float bg[5][4];
#pragma unroll
            for (int g = 0; g < 5; ++g)
#pragma unroll
                for (int r = 0; r < 4; ++r)
                    bg[g][r] = tbl2[bkt + 16 * g - 48 - r];

#pragma unroll
            for (int qh = 0; qh < 2; ++qh) {
                f32x4 z = {0.f, 0.f, 0.f, 0.f};
                f32x4 s[4];
#pragma unroll
                for (int j = 0; j < 4; ++j) s[j] = MFMA16(kf[j], qf[qh], z);
#pragma unroll
                for (int j = 0; j < 4; ++j)
#pragma unroll
                    for (int r = 0; r < 4; ++r)
                        s[j][r] = hw_exp2(s[j][r] + bg[qh + 3 - j][r]);
#pragma unroll
                for (int j = 0; j < 4; ++j) {
                    union { u32 u[2]; bf16x4 v; } pj;
                    pj.u[0] = __builtin_amdgcn_perm(__float_as_uint(s[j][1]),
                                                    __float_as_uint(s[j][0]), 0x07060302u);
                    pj.u[1] = __builtin_amdgcn_perm(__float_as_uint(s[j][3]),
                                                    __float_as_uint(s[j][2]), 0x07060302u);
                    oT0[qh] = MFMAK16(va[0][j], pj.v, oT0[qh]);
                    oT1[qh] = MFMAK16(va[1][j], pj.v, oT1[qh]);
                    oL[qh]  = MFMAK16(ones4, pj.v, oL[qh]);
                }
            }
        }
        __syncthreads();  // buf reads done; next DMA drained
    }
#undef DMA
#undef GLDS

    // epilogue: unnormalized f32 partials. Opart[kh][bh][q][d]; lpart[kh][bh][q].
    float* Ob = Opart + (size_t)kh * 2097152 + (size_t)bh * 65536;
#pragma unroll
    for (int qh = 0; qh < 2; ++qh) {
        int row = qr0 + qh * 16;
#pragma unroll
        for (int dt = 0; dt < 2; ++dt) {
            const f32x4& o = dt ? oT1[qh] : oT0[qh];
            float4 w; w.x = o[0]; w.y = o[1]; w.z = o[2]; w.w = o[3];
            *(float4*)(Ob + (size_t)row * 32 + dt * 16 + quad * 4) = w;
        }
        if (quad == 0)
            lpart[(size_t)kh * 65536 + (size_t)bh * 2048 + row] = oL[qh][0];
    }
}

// ---------------- kernel 4: FUSED combine + out-GEMM ----------------
// A-fragments built inline from f32 partials: af = (O0+O1)*inv(l0+l1) -> bf16.
// Deletes k_comb (launch + 4MB write + 16MB read). inv_l precomputed in registers.
__global__ __launch_bounds__(256, 4) void k_gemm_out(const float* __restrict__ Opart,
                                                     const float* __restrict__ lpart,
                                                     const u16* __restrict__ wT,
                                                     const float* __restrict__ bout,
                                                     float* __restrict__ out) {
    const int tid = threadIdx.x;
    const int wave = tid >> 6, lane = tid & 63, quad = lane >> 4, ql = lane & 15;
    const int mbase = blockIdx.x * 128 + (wave & 1) * 64;
    const int nbase = blockIdx.y * 64 + (wave >> 1) * 32;

    // invl[ms][ks] = 1/(l0+l1) for row mbase+ms*16+ql, head ks
    float invl[4][8];
#pragma unroll
    for (int ms = 0; ms < 4; ++ms) {
        int row = mbase + ms * 16 + ql;
        int bb = row >> 11, n = row & 2047;
#pragma unroll
        for (int ks = 0; ks < 8; ++ks) {
            size_t li = (size_t)(bb * 8 + ks) * 2048 + n;
            invl[ms][ks] = 1.0f / (lpart[li] + lpart[65536 + li]);
        }
    }

    f32x4 acc[4][2];
#pragma unroll
    for (int i = 0; i < 4; ++i)
#pragma unroll
        for (int j = 0; j < 2; ++j) acc[i][j] = (f32x4){0.f, 0.f, 0.f, 0.f};
#pragma unroll
    for (int ks = 0; ks < 8; ++ks) {
        bf16x8 af[4], bfm[2];
#pragma unroll
        for (int ms = 0; ms < 4; ++ms) {
            int row = mbase + ms * 16 + ql;
            int bb = row >> 11, n = row & 2047;
            size_t base = ((size_t)(bb * 8 + ks) * 2048 + n) * 32 + quad * 8;
            float4 a0 = *(const float4*)(Opart + base);
            float4 a1 = *(const float4*)(Opart + base + 4);
            float4 b0 = *(const float4*)(Opart + 2097152 + base);
            float4 b1 = *(const float4*)(Opart + 2097152 + base + 4);
            float iv = invl[ms][ks];
            u16 e0 = f2bf((a0.x + b0.x) * iv), e1 = f2bf((a0.y + b0.y) * iv);
            u16 e2 = f2bf((a0.z + b0.z) * iv), e3 = f2bf((a0.w + b0.w) * iv);
            u16 e4 = f2bf((a1.x + b1.x) * iv), e5 = f2bf((a1.y + b1.y) * iv);
            u16 e6 = f2bf((a1.z + b1.z) * iv), e7 = f2bf((a1.w + b1.w) * iv);
            union { uint4 u; bf16x8 v; } pk;
            pk.u.x = e0 | ((u32)e1 << 16); pk.u.y = e2 | ((u32)e3 << 16);
            pk.u.z = e4 | ((u32)e5 << 16); pk.u.w = e6 | ((u32)e7 << 16);
            af[ms] = pk.v;
        }
#pragma unroll
        for (int ns = 0; ns < 2; ++ns)
            bfm[ns] = *(const bf16x8*)(wT + (size_t)(nbase + ns * 16 + ql) * 256 + ks * 32 + quad * 8);
#pragma unroll
        for (int ms = 0; ms < 4; ++ms)
#pragma unroll
            for (int ns = 0; ns < 2; ++ns)
                acc[ms][ns] = MFMA16(af[ms], bfm[ns], acc[ms][ns]);
    }
#pragma unroll
    for (int ms = 0; ms < 4; ++ms)
#pragma unroll
        for (int ns = 0; ns < 2; ++ns)
#pragma unroll
            for (int r = 0; r < 4; ++r) {
                int Mrow = mbase + ms * 16 + quad * 4 + r;
                int col = nbase + ns * 16 + ql;
                out[(size_t)Mrow * 256 + col] = acc[ms][ns][r] + bout[col];
            }
}

extern "C" void kernel_launch(void* const* d_in, const int* in_sizes, int n_in,
                              void* d_out, int out_size, void* d_ws, size_t ws_size,
                              hipStream_t stream) {
    const float* x    = (const float*)d_in[0];  // [4,2048,256] fp32
    const float* wqkv = (const float*)d_in[1];  // [256,768] fp32
    const float* btab = (const float*)d_in[2];  // [16384,1] fp32
    const float* wout = (const float*)d_in[3];  // [256,256] fp32
    const float* bout = (const float*)d_in[4];  // [256] fp32
    // d_in[5] relative_pos is Toeplitz (i - j + 2047) -- computed analytically, not read.
    float* out = (float*)d_out;                 // [4,2048,256] fp32

    // ws: [wqkvT 384K][woutT 128K][qkv 12M][Opart 16M][lpart 512K] = 30,408,704 B
    if (ws_size < (size_t)30408704) return;
    u16* ws = (u16*)d_ws;
    u16* wqkvT = ws;                     // 196,608 bf16  [768][256]
    u16* woutT = wqkvT + 196608;         // 65,536 bf16   [256][256]
    u16* qkv   = woutT + 65536;          // Q | K | V^T
    float* Opart = (float*)(qkv + 3 * 2097152);  // [2][32][2048][32] f32
    float* lpart = Opart + 4194304;              // [2][32][2048] f32
    u16* xb    = (u16*)d_out;            // bf16 scratch in d_out; consumed before k_gemm_out

    hipLaunchKernelGGL(k_prep, dim3(2048), dim3(256), 0, stream, x, wqkv, wout, xb, wqkvT, woutT);
    hipLaunchKernelGGL(k_gemm_qkv, dim3(64, 12), dim3(256), 0, stream, xb, wqkvT, qkv);
    hipLaunchKernelGGL(k_attn, dim3(1024), dim3(256), 0, stream,
                       qkv, qkv + 2097152, qkv + 2 * 2097152, btab, Opart, lpart);
    hipLaunchKernelGGL(k_gemm_out, dim3(64, 4), dim3(256), 0, stream,
                       Opart, lpart, woutT, bout, out);
}

// Round 17
// 141.327 us; speedup vs baseline: 1.1072x; 1.1072x over previous
//
#include <hip/hip_runtime.h>

typedef unsigned short u16;
typedef unsigned int u32;
typedef __attribute__((ext_vector_type(8))) short bf16x8;
typedef __attribute__((ext_vector_type(4))) short bf16x4;
typedef __attribute__((ext_vector_type(4))) float f32x4;

#define MFMA16(a, b, c) __builtin_amdgcn_mfma_f32_16x16x32_bf16(a, b, c, 0, 0, 0)
// K=16 bf16 MFMA (gfx90a-lineage "_1k" builtin, valid on gfx950 per ISA §10).
#define MFMAK16(a, b, c) __builtin_amdgcn_mfma_f32_16x16x16bf16_1k(a, b, c, 0, 0, 0)

__device__ __forceinline__ float hw_exp2(float x) { return __builtin_amdgcn_exp2f(x); }

__device__ __forceinline__ u16 f2bf(float f) {
    union { float f; u32 i; } v; v.f = f;
    u32 x = v.i;
    return (u16)((x + 0x7FFFu + ((x >> 16) & 1u)) >> 16);
}

// ---------------- kernel 1: prep ----------------
__global__ __launch_bounds__(256) void k_prep(const float* __restrict__ x,
                                              const float* __restrict__ wqkv,
                                              const float* __restrict__ wout,
                                              u16* __restrict__ xb,
                                              u16* __restrict__ wqkvT,
                                              u16* __restrict__ woutT) {
    const float QSCALE2 = 0.2550566756538019f;  // 32^-0.5 * log2(e)
    int bx = blockIdx.x, tid = threadIdx.x;
    if (bx < 1024) {
        int base = bx * 2048 + tid * 8;
        float4 a = *(const float4*)(x + base);
        float4 b = *(const float4*)(x + base + 4);
        uint4 r;
        r.x = f2bf(a.x) | ((u32)f2bf(a.y) << 16);
        r.y = f2bf(a.z) | ((u32)f2bf(a.w) << 16);
        r.z = f2bf(b.x) | ((u32)f2bf(b.y) << 16);
        r.w = f2bf(b.z) | ((u32)f2bf(b.w) << 16);
        *(uint4*)(xb + base) = r;
    } else if (bx < 1792) {
        int idx = (bx - 1024) * 256 + tid;
        int n = idx >> 8, kk = idx & 255;
        float sc = (n < 256) ? QSCALE2 : 1.0f;
        wqkvT[idx] = f2bf(wqkv[kk * 768 + n] * sc);
    } else {
        int idx = (bx - 1792) * 256 + tid;
        int n = idx >> 8, kk = idx & 255;
        woutT[idx] = f2bf(wout[kk * 256 + n]);
    }
}

// ---------------- kernel 2: qkv = xb @ w_qkv, LDS-coalesced epilogue ----------------
__global__ __launch_bounds__(256) void k_gemm_qkv(const u16* __restrict__ xb,
                                                  const u16* __restrict__ wT,
                                                  u16* __restrict__ qkv) {
    __shared__ __align__(16) u16 slds[8704];  // QK: [128][68]; V: [64][136]
    const int tid = threadIdx.x;
    const int wave = tid >> 6, lane = tid & 63, quad = lane >> 4, ql = lane & 15;
    const int mbase = blockIdx.x * 128 + (wave & 1) * 64;
    const int nbase = blockIdx.y * 64 + (wave >> 1) * 32;
    f32x4 acc[4][2];
#pragma unroll
    for (int i = 0; i < 4; ++i)
#pragma unroll
        for (int j = 0; j < 2; ++j) acc[i][j] = (f32x4){0.f, 0.f, 0.f, 0.f};
#pragma unroll
    for (int ks = 0; ks < 8; ++ks) {
        bf16x8 af[4], bfm[2];
#pragma unroll
        for (int ms = 0; ms < 4; ++ms)
            af[ms] = *(const bf16x8*)(xb + (size_t)(mbase + ms * 16 + ql) * 256 + ks * 32 + quad * 8);
#pragma unroll
        for (int ns = 0; ns < 2; ++ns)
            bfm[ns] = *(const bf16x8*)(wT + (size_t)(nbase + ns * 16 + ql) * 256 + ks * 32 + quad * 8);
#pragma unroll
        for (int ms = 0; ms < 4; ++ms)
#pragma unroll
            for (int ns = 0; ns < 2; ++ns)
                acc[ms][ns] = MFMA16(af[ms], bfm[ns], acc[ms][ns]);
    }

    const int t = (blockIdx.y * 64) >> 8;  // 0=Q, 1=K, 2=V (uniform per block)
    if (t < 2) {
        const int rowb = (wave & 1) * 64, colb = (wave >> 1) * 32;
#pragma unroll
        for (int ms = 0; ms < 4; ++ms)
#pragma unroll
            for (int ns = 0; ns < 2; ++ns)
#pragma unroll
                for (int r = 0; r < 4; ++r)
                    slds[(rowb + ms * 16 + quad * 4 + r) * 68 + colb + ns * 16 + ql] =
                        f2bf(acc[ms][ns][r]);
        __syncthreads();
        u16* base = qkv + (size_t)t * 2097152;
#pragma unroll
        for (int p = 0; p < 8; ++p) {
            int c = p * 256 + tid;
            int row = c >> 4, ch = c & 15;
            uint2 w = *(const uint2*)&slds[row * 68 + ch * 4];
            int n = blockIdx.x * 128 + row;
            int col = blockIdx.y * 64 + ch * 4;
            int h = (col & 255) >> 5, d = col & 31;
            *(uint2*)(base + ((size_t)((n >> 11) * 8 + h) * 2048 + (n & 2047)) * 32 + d) = w;
        }
    } else {
        const int hl = wave >> 1, nb = (wave & 1) * 64;
#pragma unroll
        for (int ms = 0; ms < 4; ++ms)
#pragma unroll
            for (int ns = 0; ns < 2; ++ns) {
                u16 e0 = f2bf(acc[ms][ns][0]), e1 = f2bf(acc[ms][ns][1]);
                u16 e2 = f2bf(acc[ms][ns][2]), e3 = f2bf(acc[ms][ns][3]);
                uint2 pp; pp.x = e0 | ((u32)e1 << 16); pp.y = e2 | ((u32)e3 << 16);
                *(uint2*)&slds[(hl * 32 + ns * 16 + ql) * 136 + nb + ms * 16 + quad * 4] = pp;
            }
        __syncthreads();
        u16* vbase = qkv + (size_t)2 * 2097152;
#pragma unroll
        for (int p = 0; p < 4; ++p) {
            int c = p * 256 + tid;
            int row = c >> 4, ch = c & 15;
            bf16x8 w = *(const bf16x8*)&slds[row * 136 + ch * 8];
            int n0 = blockIdx.x * 128 + ch * 8;
            int h = (blockIdx.y & 3) * 2 + (row >> 5), d = row & 31;
            *(bf16x8*)(vbase + (size_t)((n0 >> 11) * 8 + h) * 65536 +
                       (size_t)d * 2048 + (n0 & 2047)) = w;
        }
    }
}

// ---------------- kernel 3: flash attention, DMA K/V, register P (no pT LDS) --------------
// grid 512: bh = bx&31, qt = bx>>5. Block 4 waves; wave = 32 q-rows (2 qh).
// KEY IDENTITY: mfma_f32_16x16x16_bf16's B-fragment (n=ql, k=quad*4+reg) == the C/D layout
// of the S^T tiles (col=ql, row=quad*4+r). So P^T feeds PV straight from registers.
// Bias gathers use the (qh-j) overlap: 5 groups of 4 instead of 8.
// DMA double-buffer staging identical to round 10/11 (the proven structure).
__global__ __launch_bounds__(256, 2) void k_attn(const u16* __restrict__ q,
                                                 const u16* __restrict__ k,
                                                 const u16* __restrict__ vT,
                                                 const float* __restrict__ table,
                                                 u16* __restrict__ att) {
    __shared__ __align__(16) u16 kbuf[2][2][2048];  // [buf][tile][swizzled 64x32]
    __shared__ __align__(16) u16 vbuf[2][2][2048];  // [buf][tile][32 d][64 n swizzled 8-chunks]
    __shared__ float tbl2[2176];
    const int tid = threadIdx.x;
    const int bh = blockIdx.x & 31, qt = blockIdx.x >> 5;
    const int wave = tid >> 6, lane = tid & 63, quad = lane >> 4, ql = lane & 15;
    const float LOG2E = 1.4426950408889634f;

    const u16* kbh = k + (size_t)bh * 65536;
    const u16* vbh = vT + (size_t)bh * 65536;  // [32 d][2048 n]

    // DMA lane->global maps (LDS side forced contiguous: base + lane*16B).
    const int krow = wave * 16 + (lane >> 2);
    const u16* kg = kbh + krow * 32 + ((((lane & 3) ^ ((lane >> 3) & 3))) << 3);
    const int vd = wave * 8 + (lane >> 3);
    const u16* vg = vbh + (size_t)vd * 2048 + (((lane & 7) ^ (vd & 7)) << 3);

#define GLDS(SRC, DST) __builtin_amdgcn_global_load_lds(                         \
        (const __attribute__((address_space(1))) void*)(SRC),                    \
        (__attribute__((address_space(3))) void*)(DST), 16, 0, 0)
#define DMA(BUF, PAIR) do {                                                      \
    GLDS(kg + (PAIR) * 4096,        &kbuf[BUF][0][wave * 512]);                  \
    GLDS(kg + (PAIR) * 4096 + 2048, &kbuf[BUF][1][wave * 512]);                  \
    GLDS(vg + (PAIR) * 128,         &vbuf[BUF][0][wave * 512]);                  \
    GLDS(vg + (PAIR) * 128 + 64,    &vbuf[BUF][1][wave * 512]);                  \
} while (0)

    DMA(0, 0);  // pair 0 in flight during bias staging

    // bias window: idx = q - kv + 2047 - qt*128 in [0, 2174]
    const float4* tg = (const float4*)(table + qt * 128);
    for (int i = tid; i < 544; i += 256) {
        float4 t = tg[i];
        t.x *= LOG2E; t.y *= LOG2E; t.z *= LOG2E; t.w *= LOG2E;
        ((float4*)tbl2)[i] = t;
    }

    const int qr0 = qt * 128 + wave * 32 + ql;
    bf16x8 qf[2];
    qf[0] = *(const bf16x8*)(q + ((size_t)bh * 2048 + qr0) * 32 + quad * 8);
    qf[1] = *(const bf16x8*)(q + ((size_t)bh * 2048 + qr0 + 16) * 32 + quad * 8);
    const int bloc0 = wave * 32 + ql + 2047 - quad * 4;
    const int kro = ((quad ^ ((ql >> 1) & 3)) << 3);    // K read swizzle offset

    bf16x4 ones4;
#pragma unroll
    for (int i = 0; i < 4; ++i) ones4[i] = (short)0x3F80;  // bf16 1.0

    f32x4 oT0[2], oT1[2], oL[2];
#pragma unroll
    for (int qh = 0; qh < 2; ++qh) {
        oT0[qh] = (f32x4){0.f, 0.f, 0.f, 0.f};
        oT1[qh] = (f32x4){0.f, 0.f, 0.f, 0.f};
        oL[qh]  = (f32x4){0.f, 0.f, 0.f, 0.f};
    }

    __syncthreads();  // bias + pair 0 ready

    for (int pr = 0; pr < 16; ++pr) {
        const int buf = pr & 1;
        if (pr < 15) DMA(buf ^ 1, pr + 1);  // lands during this 2-tile body

#pragma unroll
        for (int t = 0; t < 2; ++t) {
            const int kt = pr * 2 + t;
            const u16* kb = &kbuf[buf][t][0];
            const u16* vb = &vbuf[buf][t][0];
            bf16x8 kf[4];
            bf16x4 va[2][4];  // [d-tile][j]: A-frag of V^T, k = quad*4 + reg
#pragma unroll
            for (int j = 0; j < 4; ++j)
                kf[j] = *(const bf16x8*)(kb + (j * 16 + ql) * 32 + kro);
#pragma unroll
            for (int dt = 0; dt < 2; ++dt)
#pragma unroll
                for (int j = 0; j < 4; ++j) {
                    int nloc = j * 16 + quad * 4;           // n-local base of this A-frag
                    int slot = (nloc >> 3) ^ (ql & 7);      // V chunk swizzle
                    va[dt][j] = *(const bf16x4*)(vb + (dt * 16 + ql) * 64 +
                                                 slot * 8 + (nloc & 7));
                }
            // bias groups: grp = qh - j + 3 in 0..4; bg[grp][r] = tbl2[bkt + 16*(grp-3) - r]
            const int bkt = bloc0 - kt * 64;
            float bg[5][4];
#pragma unroll
            for (int g = 0; g < 5; ++g)
#pragma unroll
                for (int r = 0; r < 4; ++r)
                    bg[g][r] = tbl2[bkt + 16 * g - 48 - r];

#pragma unroll
            for (int qh = 0; qh < 2; ++qh) {
                f32x4 z = {0.f, 0.f, 0.f, 0.f};
                f32x4 s[4];
#pragma unroll
                for (int j = 0; j < 4; ++j) s[j] = MFMA16(kf[j], qf[qh], z);
#pragma unroll
                for (int j = 0; j < 4; ++j)
#pragma unroll
                    for (int r = 0; r < 4; ++r)
                        s[j][r] = hw_exp2(s[j][r] + bg[qh + 3 - j][r]);
#pragma unroll
                for (int j = 0; j < 4; ++j) {
                    union { u32 u[2]; bf16x4 v; } pj;
                    pj.u[0] = __builtin_amdgcn_perm(__float_as_uint(s[j][1]),
                                                    __float_as_uint(s[j][0]), 0x07060302u);
                    pj.u[1] = __builtin_amdgcn_perm(__float_as_uint(s[j][3]),
                                                    __float_as_uint(s[j][2]), 0x07060302u);
                    oT0[qh] = MFMAK16(va[0][j], pj.v, oT0[qh]);
                    oT1[qh] = MFMAK16(va[1][j], pj.v, oT1[qh]);
                    oL[qh]  = MFMAK16(ones4, pj.v, oL[qh]);
                }
            }
        }
        __syncthreads();  // buf reads done; next DMA drained
    }
#undef DMA
#undef GLDS

    // epilogue: every oL reg holds l for q-col=ql; no shuffles needed
#pragma unroll
    for (int qh = 0; qh < 2; ++qh) {
        float inv = 1.0f / oL[qh][0];
        size_t base = ((size_t)bh * 2048 + qr0 + qh * 16) * 32;
#pragma unroll
        for (int dt = 0; dt < 2; ++dt) {
            const f32x4& o = dt ? oT1[qh] : oT0[qh];
            u16 e0 = f2bf(o[0] * inv), e1 = f2bf(o[1] * inv);
            u16 e2 = f2bf(o[2] * inv), e3 = f2bf(o[3] * inv);
            uint2 pp; pp.x = e0 | ((u32)e1 << 16); pp.y = e2 | ((u32)e3 << 16);
            *(uint2*)(att + base + dt * 16 + quad * 4) = pp;
        }
    }
}

// ---------------- kernel 4: out = att @ w_out + b_out -> fp32 d_out ----------------
__global__ __launch_bounds__(256) void k_gemm_out(const u16* __restrict__ attq,
                                                  const u16* __restrict__ wT,
                                                  const float* __restrict__ bout,
                                                  float* __restrict__ out) {
    const int tid = threadIdx.x;
    const int wave = tid >> 6, lane = tid & 63, quad = lane >> 4, ql = lane & 15;
    const int mbase = blockIdx.x * 128 + (wave & 1) * 64;
    const int nbase = blockIdx.y * 64 + (wave >> 1) * 32;
    f32x4 acc[4][2];
#pragma unroll
    for (int i = 0; i < 4; ++i)
#pragma unroll
        for (int j = 0; j < 2; ++j) acc[i][j] = (f32x4){0.f, 0.f, 0.f, 0.f};
#pragma unroll
    for (int ks = 0; ks < 8; ++ks) {
        bf16x8 af[4], bfm[2];
#pragma unroll
        for (int ms = 0; ms < 4; ++ms) {
            int row = mbase + ms * 16 + ql;
            af[ms] = *(const bf16x8*)(attq +
                ((size_t)((row >> 11) * 8 + ks) * 2048 + (row & 2047)) * 32 + quad * 8);
        }
#pragma unroll
        for (int ns = 0; ns < 2; ++ns)
            bfm[ns] = *(const bf16x8*)(wT + (size_t)(nbase + ns * 16 + ql) * 256 + ks * 32 + quad * 8);
#pragma unroll
        for (int ms = 0; ms < 4; ++ms)
#pragma unroll
            for (int ns = 0; ns < 2; ++ns)
                acc[ms][ns] = MFMA16(af[ms], bfm[ns], acc[ms][ns]);
    }
#pragma unroll
    for (int ms = 0; ms < 4; ++ms)
#pragma unroll
        for (int ns = 0; ns < 2; ++ns)
#pragma unroll
            for (int r = 0; r < 4; ++r) {
                int Mrow = mbase + ms * 16 + quad * 4 + r;
                int col = nbase + ns * 16 + ql;
                out[(size_t)Mrow * 256 + col] = acc[ms][ns][r] + bout[col];
            }
}

extern "C" void kernel_launch(void* const* d_in, const int* in_sizes, int n_in,
                              void* d_out, int out_size, void* d_ws, size_t ws_size,
                              hipStream_t stream) {
    const float* x    = (const float*)d_in[0];  // [4,2048,256] fp32
    const float* wqkv = (const float*)d_in[1];  // [256,768] fp32
    const float* btab = (const float*)d_in[2];  // [16384,1] fp32
    const float* wout = (const float*)d_in[3];  // [256,256] fp32
    const float* bout = (const float*)d_in[4];  // [256] fp32
    // d_in[5] relative_pos is Toeplitz (i - j + 2047) -- computed analytically, not read.
    float* out = (float*)d_out;                 // [4,2048,256] fp32

    // ws layout (bytes): [wqkvT 393216][woutT 131072][qkv 12582912] = 13,107,200 total
    if (ws_size < (size_t)13107200) return;
    u16* ws = (u16*)d_ws;
    u16* wqkvT = ws;                   // 196,608 bf16  [768][256]
    u16* woutT = wqkvT + 196608;       // 65,536 bf16   [256][256]
    u16* qkv   = woutT + 65536;        // Q [B*H][N][D] | K [B*H][N][D] | V^T [B*H][D][N]
    u16* xb    = (u16*)d_out;          // bf16 scratch in d_out; consumed before k_gemm_out

    hipLaunchKernelGGL(k_prep, dim3(2048), dim3(256), 0, stream, x, wqkv, wout, xb, wqkvT, woutT);
    hipLaunchKernelGGL(k_gemm_qkv, dim3(64, 12), dim3(256), 0, stream, xb, wqkvT, qkv);
    // k_attn writes its output (bf16, [B*H][N][D]) back into the Q third of qkv.
    hipLaunchKernelGGL(k_attn, dim3(512), dim3(256), 0, stream,
                       qkv, qkv + 2097152, qkv + 2 * 2097152, btab, qkv);
    hipLaunchKernelGGL(k_gemm_out, dim3(64, 4), dim3(256), 0, stream, qkv, woutT, bout, out);
}